// Round 1
// baseline (24.946 us; speedup 1.0000x reference)
//
#include <hip/hip_runtime.h>

// Bootstrap proposal (time != 0 branch), constants folded for L1=L2=M1=M2=1:
//   c   = cos(theta2)
//   d00 = (5 + 3c)/3, d01 = (3c + 2)/6, d11 = 1/3
//   det = d00*d11 - d01^2
//   a1  = (d11*tq1 - d01*tq2)/det
//   a2  = (d00*tq2 - d01*tq1)/det
//   mean = prev + DT*[0, 0, v1, v2, a1, a2]
// Layout is AoS [B*P, 6] f32. Two particles = 48 B = 3 float4 -> one thread
// handles a particle pair with 3 aligned float4 loads + 3 float4 stores.

#define DT 0.01f

__device__ __forceinline__ void particle_step(
    float tq1, float tq2, float th1, float th2, float v1, float v2,
    float& m0, float& m1, float& m2, float& m3, float& m4, float& m5) {
    const float c   = __cosf(th2) ;
    // NOTE: __cosf is fast-approx; use precise cosf for safety instead.
    const float cc  = cosf(th2);
    (void)c;
    const float d00 = (5.0f + 3.0f * cc) * (1.0f / 3.0f);
    const float d01 = (3.0f * cc + 2.0f) * (1.0f / 6.0f);
    const float d11 = (1.0f / 3.0f);
    const float det = d00 * d11 - d01 * d01;
    const float a1  = (d11 * tq1 - d01 * tq2) / det;
    const float a2  = (d00 * tq2 - d01 * tq1) / det;
    m0 = tq1;
    m1 = tq2;
    m2 = th1 + DT * v1;
    m3 = th2 + DT * v2;
    m4 = v1 + DT * a1;
    m5 = v2 + DT * a2;
}

__global__ void __launch_bounds__(256)
bootstrap_proposal_kernel(const float4* __restrict__ in4,
                          float4* __restrict__ out4,
                          int npairs) {
    int j = blockIdx.x * blockDim.x + threadIdx.x;
    if (j >= npairs) return;

    const float4 v0 = in4[3 * j + 0];  // p0: tq1 tq2 th1 th2
    const float4 v1 = in4[3 * j + 1];  // p0: v1 v2 | p1: tq1 tq2
    const float4 v2 = in4[3 * j + 2];  // p1: th1 th2 v1 v2

    float4 o0, o1, o2;
    // particle 0
    particle_step(v0.x, v0.y, v0.z, v0.w, v1.x, v1.y,
                  o0.x, o0.y, o0.z, o0.w, o1.x, o1.y);
    // particle 1
    particle_step(v1.z, v1.w, v2.x, v2.y, v2.z, v2.w,
                  o1.z, o1.w, o2.x, o2.y, o2.z, o2.w);

    out4[3 * j + 0] = o0;
    out4[3 * j + 1] = o1;
    out4[3 * j + 2] = o2;
}

extern "C" void kernel_launch(void* const* d_in, const int* in_sizes, int n_in,
                              void* d_out, int out_size, void* d_ws, size_t ws_size,
                              hipStream_t stream) {
    const float* in = (const float*)d_in[0];   // [B*P, 6] f32
    float* out = (float*)d_out;                // [B*P, 6] f32
    // out_size = B*P*6; particles = out_size/6; pairs = particles/2
    const int npairs = out_size / 12;
    const int block = 256;
    const int grid = (npairs + block - 1) / block;
    bootstrap_proposal_kernel<<<grid, block, 0, stream>>>(
        (const float4*)in, (float4*)out, npairs);
}

// Round 2
// 20.751 us; speedup vs baseline: 1.2022x; 1.2022x over previous
//
#include <hip/hip_runtime.h>

// Bootstrap proposal (time != 0 branch), constants folded for L1=L2=M1=M2=1.
// Per particle [tq1, tq2, th1, th2, v1, v2]:
//   c  = cos(th2)
//   36*det = 16 - 9c^2
//   a1 = (12*tq1 - 6*(3c+2)*tq2) / (16 - 9c^2)
//   a2 = (12*(5+3c)*tq2 - 6*(3c+2)*tq1) / (16 - 9c^2)
//   mean = prev + DT*[0, 0, v1, v2, a1, a2]
//
// AoS [B*P, 6] f32. One thread per particle PAIR (48 B = 3 float4).
// Direct strided float4 access (48 B lane stride) only reached 4.0 TB/s;
// this version stages through LDS so all global accesses are lane-contiguous:
//   load  : lds[k*256+t] = in4[base + k*256 + t]   (coalesced, k=0..2)
//   read  : 3x ds_read_b128 at dword offset 12*t   (48B lane stride tiles all
//           32 banks once per 8 lanes -> conflict-free)
//   write : in-place to same LDS slots (thread-private, no hazard)
//   store : out4[base + k*256 + t] = lds[k*256+t]  (coalesced)

#define DT 0.01f

__device__ __forceinline__ void particle_step(
    float tq1, float tq2, float th1, float th2, float v1, float v2,
    float& m0, float& m1, float& m2, float& m3, float& m4, float& m5) {
    const float c    = cosf(th2);
    const float rden = 1.0f / (16.0f - 9.0f * c * c);   // = 1/(36*det)
    const float s    = 6.0f * (3.0f * c + 2.0f);        // = 36*d01
    const float a1   = (12.0f * tq1 - s * tq2) * rden;
    const float a2   = (12.0f * (5.0f + 3.0f * c) * tq2 - s * tq1) * rden;
    m0 = tq1;
    m1 = tq2;
    m2 = th1 + DT * v1;
    m3 = th2 + DT * v2;
    m4 = v1 + DT * a1;
    m5 = v2 + DT * a2;
}

__global__ void __launch_bounds__(256)
bootstrap_proposal_kernel(const float4* __restrict__ in4,
                          float4* __restrict__ out4,
                          long long nvec) {
    __shared__ float4 lds[768];   // 256 pairs * 3 float4 = 12 KB
    const int t = threadIdx.x;
    const long long base = (long long)blockIdx.x * 768;

    // Coalesced global -> LDS
#pragma unroll
    for (int k = 0; k < 3; ++k) {
        const long long idx = base + k * 256 + t;
        if (idx < nvec) lds[k * 256 + t] = in4[idx];
    }
    __syncthreads();

    // Per-thread pair from LDS (conflict-free b128 pattern), compute in place
    const float4 v0 = lds[3 * t + 0];  // p0: tq1 tq2 th1 th2
    const float4 v1 = lds[3 * t + 1];  // p0: v1 v2 | p1: tq1 tq2
    const float4 v2 = lds[3 * t + 2];  // p1: th1 th2 v1 v2

    float4 o0, o1, o2;
    particle_step(v0.x, v0.y, v0.z, v0.w, v1.x, v1.y,
                  o0.x, o0.y, o0.z, o0.w, o1.x, o1.y);
    particle_step(v1.z, v1.w, v2.x, v2.y, v2.z, v2.w,
                  o1.z, o1.w, o2.x, o2.y, o2.z, o2.w);

    lds[3 * t + 0] = o0;
    lds[3 * t + 1] = o1;
    lds[3 * t + 2] = o2;
    __syncthreads();

    // Coalesced LDS -> global
#pragma unroll
    for (int k = 0; k < 3; ++k) {
        const long long idx = base + k * 256 + t;
        if (idx < nvec) out4[idx] = lds[k * 256 + t];
    }
}

extern "C" void kernel_launch(void* const* d_in, const int* in_sizes, int n_in,
                              void* d_out, int out_size, void* d_ws, size_t ws_size,
                              hipStream_t stream) {
    const float* in = (const float*)d_in[0];   // [B*P, 6] f32
    float* out = (float*)d_out;                // [B*P, 6] f32
    const long long nvec = (long long)out_size / 4;        // total float4
    const int grid = (int)((nvec + 767) / 768);            // 768 float4 / block
    bootstrap_proposal_kernel<<<grid, 256, 0, stream>>>(
        (const float4*)in, (float4*)out, nvec);
}